// Round 10
// baseline (168.218 us; speedup 1.0000x reference)
//
#include <hip/hip_runtime.h>

typedef _Float16 f16x8 __attribute__((ext_vector_type(8)));
typedef _Float16 f16x4 __attribute__((ext_vector_type(4)));
typedef _Float16 h2   __attribute__((ext_vector_type(2)));
typedef float f32x4 __attribute__((ext_vector_type(4)));

__device__ __forceinline__ void gload16(const void* g, void* l) {
  __builtin_amdgcn_global_load_lds(
      (__attribute__((address_space(1))) void*)g,
      (__attribute__((address_space(3))) void*)l, 16, 0, 0);
}

// W is scaled by 2^12 when cast to f16 (raw ~1e-5 values are f16-subnormal;
// denormal flush would delete the r@W term). Epilogue multiplies by 2^-12.
#define W_SCALE 4096.0f
#define W_UNSCALE (1.0f / 4096.0f)

// "Island" layout (LDS-fragment-exact), used for W_in (B operand):
// element (row,k) -> (row>>4)*50176 + (k>>5)*512 + ((k>>3)&3)*128 + (row&15)*8 + (k&7)
#define ISL(row, k) (((row) >> 4) * 50176 + ((k) >> 5) * 512 + \
                     ((((k) >> 3) & 3) << 7) + (((row) & 15) << 3) + ((k) & 7))

// ---------------- conv 3x3 (1->16) + bias + relu + maxpool2 -> conv_flat (plain) ----------
__global__ __launch_bounds__(256) void conv_pool_kernel(
    const float* __restrict__ x,      // [8192][28][28]
    const float* __restrict__ cw,     // [16][9]
    const float* __restrict__ cb,     // [16]
    _Float16* __restrict__ out) {     // [8192][3136] plain (c*196 + p)
  __shared__ float img[30 * 32];      // padded 30 rows x 32 cols (row/col +1 offset)
  __shared__ h2 wsm[144];
  __shared__ h2 bsm[16];
  int tid = threadIdx.x;
  for (int i = tid; i < 960; i += 256) img[i] = 0.f;
  if (tid < 144) { float w = cw[tid]; wsm[tid] = h2{(_Float16)w, (_Float16)w}; }
  if (tid < 16)  { float b = cb[tid]; bsm[tid] = h2{(_Float16)b, (_Float16)b}; }
  __syncthreads();
  if (tid < 196) {                    // 28 rows x 7 float4 per row
    float4 v = *(const float4*)(x + (size_t)blockIdx.x * 784 + tid * 4);
    int row = tid / 7, col4 = (tid - row * 7) * 4;
    float* dst = img + (row + 1) * 32 + col4 + 1;
    dst[0] = v.x; dst[1] = v.y; dst[2] = v.z; dst[3] = v.w;
  }
  __syncthreads();
  if (tid >= 196) return;
  int ph = tid / 14, pw = tid - ph * 14;
  const float* base = img + (2 * ph) * 32 + (2 * pw);
  h2 xp[4][3];
#pragma unroll
  for (int i = 0; i < 4; ++i) {
    float r0 = base[i * 32 + 0], r1 = base[i * 32 + 1];
    float r2 = base[i * 32 + 2], r3 = base[i * 32 + 3];
    xp[i][0] = h2{(_Float16)r0, (_Float16)r1};
    xp[i][1] = h2{(_Float16)r1, (_Float16)r2};
    xp[i][2] = h2{(_Float16)r2, (_Float16)r3};
  }
  _Float16* orow = out + (size_t)blockIdx.x * 3136 + tid;
#pragma unroll
  for (int ch = 0; ch < 16; ++ch) {
    h2 a01 = bsm[ch], a23 = bsm[ch];
#pragma unroll
    for (int i = 0; i < 3; ++i)
#pragma unroll
      for (int j = 0; j < 3; ++j) {
        h2 wv = wsm[ch * 9 + i * 3 + j];
        a01 = __builtin_elementwise_fma(wv, xp[i][j], a01);
        a23 = __builtin_elementwise_fma(wv, xp[i + 1][j], a23);
      }
    h2 m2 = __builtin_elementwise_max(a01, a23);
    _Float16 m = m2[0] > m2[1] ? m2[0] : m2[1];
    m = m > (_Float16)0.f ? m : (_Float16)0.f;
    orow[ch * 196] = m;
  }
}

// ---------------- prep: W_in -> island f16  |  W -> Wt f16 (n-major, *2^12) -------------
// grid 512: blocks 0..255 = win_cvt (n = blockIdx), 256..511 = wt_cvt
__global__ __launch_bounds__(256) void prep_kernel(
    const float* __restrict__ W_in, _Float16* __restrict__ W_in_h,
    const float* __restrict__ W, _Float16* __restrict__ Wt) {
  int b = blockIdx.x, tid = threadIdx.x;
  if (b < 256) {
    const float* src = W_in + (size_t)b * 3136;
#pragma unroll
    for (int it = 0; it < 4; ++it) {
      int idx = it * 256 + tid;          // float4 index, 784 per row
      if (idx < 784) {
        int k0 = idx * 4;
        float4 v = *(const float4*)(src + k0);
        f16x4 h = {(_Float16)v.x, (_Float16)v.y, (_Float16)v.z, (_Float16)v.w};
        *(f16x4*)(W_in_h + ISL(b, k0)) = h;
      }
    }
  } else {
    int i = (b - 256) * 256 + tid;       // 65536
    int k = i >> 8, n = i & 255;         // coalesced read of W row k
    Wt[n * 256 + k] = (_Float16)(W[k * 256 + n] * W_SCALE);
  }
}

// ---------------- GEMM1 split-K=2: Zz = A @ W_in^T, double-buffered 1-barrier/step -------
// grid (128,2,2); tile 64x128, BK=32, 49 steps; 4 waves x (32x64 = 2x4 frags).
// A: plain global -> island LDS via PER-LANE-ADDRESS global_load_lds.
// B: island global -> global_load_lds linear. Stage t+1 issued before compute t.
__global__ __launch_bounds__(256) void gemm1_kernel(
    const _Float16* __restrict__ A,   // plain [8192][3136]
    const _Float16* __restrict__ Bw,  // island, logical [256][3136]
    float* __restrict__ Z) {          // [2][8192][256] partials
  __shared__ __align__(16) _Float16 As[2][2048];   // 4 chunks [kg][row][8] x dbuf
  __shared__ __align__(16) _Float16 Bs[2][4096];   // 8 chunks x dbuf
  int tid = threadIdx.x, lane = tid & 63, wid = tid >> 6;
  int bm = blockIdx.x * 64, bn = blockIdx.y * 128;
  int k0 = blockIdx.z * 1568;
  f32x4 acc[2][4];
#pragma unroll
  for (int i = 0; i < 2; ++i)
#pragma unroll
    for (int j = 0; j < 4; ++j) acc[i][j] = (f32x4){0.f, 0.f, 0.f, 0.f};

  // staging addresses: wave w stages A-chunk w, B-chunks {2w, 2w+1}
  // A per-lane: lane l -> row w*16+(l&15), k-slice (l>>4)*8  (16B aligned)
  const _Float16* Ag  = A + (size_t)(bm + wid * 16 + (lane & 15)) * 3136
                          + k0 + ((lane >> 4) << 3);
  const _Float16* Bg0 = Bw + (size_t)((bn >> 4) + 2 * wid) * 50176
                          + ((k0 >> 5) << 9) + lane * 8;
  const _Float16* Bg1 = Bg0 + 50176;

  int rko = ((lane >> 4) << 7) + ((lane & 15) << 3);
  int ga = (wid & 1) * 2, gb = (wid >> 1) * 4;

  // prologue: stage t=0 into buf0
  gload16(Ag,  &As[0][wid * 512]);
  gload16(Bg0, &Bs[0][2 * wid * 512]);
  gload16(Bg1, &Bs[0][2 * wid * 512 + 512]);
  __syncthreads();                     // drain: buf0 ready

  int cur = 0;
  for (int t = 0; t < 49; ++t) {
    if (t < 48) {                      // stage t+1 into other buffer, issued EARLY
      gload16(Ag + (t + 1) * 32,            &As[cur ^ 1][wid * 512]);
      gload16(Bg0 + (size_t)(t + 1) * 512,  &Bs[cur ^ 1][2 * wid * 512]);
      gload16(Bg1 + (size_t)(t + 1) * 512,  &Bs[cur ^ 1][2 * wid * 512 + 512]);
    }
    f16x8 af0 = *(const f16x8*)(&As[cur][(ga + 0) * 512 + rko]);
    f16x8 af1 = *(const f16x8*)(&As[cur][(ga + 1) * 512 + rko]);
#pragma unroll
    for (int ni = 0; ni < 4; ++ni) {
      f16x8 bf = *(const f16x8*)(&Bs[cur][(gb + ni) * 512 + rko]);
      acc[0][ni] = __builtin_amdgcn_mfma_f32_16x16x32_f16(af0, bf, acc[0][ni], 0, 0, 0);
      acc[1][ni] = __builtin_amdgcn_mfma_f32_16x16x32_f16(af1, bf, acc[1][ni], 0, 0, 0);
    }
    __syncthreads();                   // single barrier: drains stage(t+1), guards buf reuse
    cur ^= 1;
  }

  float* Zp = Z + (size_t)blockIdx.z * 8192 * 256;
  int wm = (wid & 1) * 32, wn = (wid >> 1) * 64;
  int rg = (lane >> 4) * 4, cl = lane & 15;
#pragma unroll
  for (int mi = 0; mi < 2; ++mi)
#pragma unroll
    for (int ni = 0; ni < 4; ++ni)
#pragma unroll
      for (int j = 0; j < 4; ++j) {
        int m = bm + wm + mi * 16 + rg + j;
        int n = bn + wn + ni * 16 + cl;
        Zp[(size_t)m * 256 + n] = acc[mi][ni][j];
      }
}

// ---------------- persistent RNN: r0=relu(Z0+Z1+b); 9x r=relu(r@W+b+r); out-proj -------
__global__ __launch_bounds__(512, 2) void rnn_persist_kernel(
    const float*    __restrict__ Z0,   // [8192][256] k-half 0 partial
    const float*    __restrict__ Z1,   // [8192][256] k-half 1 partial
    const _Float16* __restrict__ Wt,   // [256][256] n-major, *2^12
    const float*    __restrict__ b_in, // [256]
    const float*    __restrict__ Wo,   // [10][256]
    const float*    __restrict__ bo,   // [10]
    float*          __restrict__ out)  // [8192][10]
{
  // element (row,k) stored at row*256 + (k ^ ((row&7)<<3))  [16B-granular]
  __shared__ __align__(16) _Float16 r_lds[32 * 256];
  int tid = threadIdx.x, lane = tid & 63, wid = tid >> 6;
  int wr = wid >> 2, wc = wid & 3;       // 2M x 4N wave grid; region 16r x 64c
  int bm = blockIdx.x * 32;

  // ---- W fragments -> registers (one-time) ----
  f16x8 wfr[8][4];
#pragma unroll
  for (int kk = 0; kk < 8; ++kk)
#pragma unroll
    for (int ni = 0; ni < 4; ++ni) {
      int n = wc * 64 + ni * 16 + (lane & 15);
      int kpos = kk * 32 + (lane >> 4) * 8;
      wfr[kk][ni] = *(const f16x8*)(Wt + n * 256 + kpos);
    }

  // ---- bias + f32 residual r0 = relu(Z0+Z1+b) -> registers ----
  float breg[4];
  float rres[4][4];
  int rrow = wr * 16 + (lane >> 4) * 4;
#pragma unroll
  for (int ni = 0; ni < 4; ++ni) {
    int col = wc * 64 + ni * 16 + (lane & 15);
    breg[ni] = b_in[col];
#pragma unroll
    for (int j = 0; j < 4; ++j) {
      size_t idx = (size_t)(bm + rrow + j) * 256 + col;
      rres[ni][j] = fmaxf(Z0[idx] + Z1[idx] + breg[ni], 0.f);
    }
  }

  // ---- r0 f16 -> LDS (swizzled): 1024 vec8, 512 threads x 2 ----
#pragma unroll
  for (int it = 0; it < 2; ++it) {
    int idx = it * 512 + tid;            // 0..1023
    int row = idx >> 5;                  // 0..31
    int kc = (idx & 31) * 8;             // 0..248
    size_t off = (size_t)(bm + row) * 256 + kc;
    f32x4 a0 = *(const f32x4*)(Z0 + off);
    f32x4 a1 = *(const f32x4*)(Z0 + off + 4);
    f32x4 b0 = *(const f32x4*)(Z1 + off);
    f32x4 b1 = *(const f32x4*)(Z1 + off + 4);
    f32x4 c0 = *(const f32x4*)(b_in + kc);
    f32x4 c1 = *(const f32x4*)(b_in + kc + 4);
    f16x8 h;
#pragma unroll
    for (int j = 0; j < 4; ++j) h[j] = (_Float16)fmaxf(a0[j] + b0[j] + c0[j], 0.f);
#pragma unroll
    for (int j = 0; j < 4; ++j) h[4 + j] = (_Float16)fmaxf(a1[j] + b1[j] + c1[j], 0.f);
    *(f16x8*)(r_lds + row * 256 + (kc ^ ((row & 7) << 3))) = h;
  }

  int arow = wr * 16 + (lane & 15);
  int aswz = (arow & 7) << 3;
  for (int s = 0; s < 9; ++s) {
    __syncthreads();                     // r_lds writes visible
    f32x4 acc[4];
#pragma unroll
    for (int ni = 0; ni < 4; ++ni) acc[ni] = (f32x4){0.f, 0.f, 0.f, 0.f};
#pragma unroll
    for (int kk = 0; kk < 8; ++kk) {
      int kpos = kk * 32 + (lane >> 4) * 8;
      f16x8 af = *(const f16x8*)(r_lds + arow * 256 + (kpos ^ aswz));
#pragma unroll
      for (int ni = 0; ni < 4; ++ni)
        acc[ni] = __builtin_amdgcn_mfma_f32_16x16x32_f16(af, wfr[kk][ni], acc[ni], 0, 0, 0);
    }
    __syncthreads();                     // all reads done before overwrite
#pragma unroll
    for (int ni = 0; ni < 4; ++ni) {
      int col = wc * 64 + ni * 16 + (lane & 15);
#pragma unroll
      for (int j = 0; j < 4; ++j) {
        float v = fmaxf(fmaf(acc[ni][j], W_UNSCALE, breg[ni] + rres[ni][j]), 0.f);
        rres[ni][j] = v;
        int row = rrow + j;
        r_lds[row * 256 + (col ^ ((row & 7) << 3))] = (_Float16)v;
      }
    }
  }
  __syncthreads();

  // ---- fused out-proj: out[32r][10] = r @ Wo^T + bo ----
  if (tid < 320) {
    int row = tid / 10, o = tid - row * 10;
    int rswz = (row & 7) << 3;
    float accd = 0.f;
    for (int kc = 0; kc < 256; kc += 8) {
      f16x8 rv = *(const f16x8*)(r_lds + row * 256 + (kc ^ rswz));
      const float* wp = Wo + o * 256 + kc;
#pragma unroll
      for (int j = 0; j < 8; ++j) accd = fmaf((float)rv[j], wp[j], accd);
    }
    out[(size_t)(bm + row) * 10 + o] = accd + bo[o];
  }
}

extern "C" void kernel_launch(void* const* d_in, const int* in_sizes, int n_in,
                              void* d_out, int out_size, void* d_ws, size_t ws_size,
                              hipStream_t stream) {
  const float* x      = (const float*)d_in[0];
  const float* conv_w = (const float*)d_in[1];
  const float* conv_b = (const float*)d_in[2];
  const float* W_in   = (const float*)d_in[3];
  const float* b_in   = (const float*)d_in[4];
  const float* W_out  = (const float*)d_in[5];
  const float* b_out  = (const float*)d_in[6];
  const float* W      = (const float*)d_in[7];
  float* out = (float*)d_out;

  char* ws = (char*)d_ws;
  size_t o = 0;
  _Float16* conv_flat = (_Float16*)(ws + o); o += (size_t)8192 * 3136 * 2;  // 51.4MB plain
  _Float16* W_in_h    = (_Float16*)(ws + o); o += (size_t)256 * 3136 * 2;   //  1.6MB island
  _Float16* Wt_h      = (_Float16*)(ws + o); o += (size_t)256 * 256 * 2;    //  0.13MB
  float*    Z01       = (float*)(ws + o);    o += (size_t)2 * 8192 * 256 * 4; // 16.8MB partials

  prep_kernel<<<512, 256, 0, stream>>>(W_in, W_in_h, W, Wt_h);
  conv_pool_kernel<<<8192, 256, 0, stream>>>(x, conv_w, conv_b, conv_flat);
  gemm1_kernel<<<dim3(128, 2, 2), 256, 0, stream>>>(conv_flat, W_in_h, Z01);
  rnn_persist_kernel<<<256, 512, 0, stream>>>(Z01, Z01 + (size_t)8192 * 256,
                                              Wt_h, b_in, W_out, b_out, out);
}

// Round 11
// 166.966 us; speedup vs baseline: 1.0075x; 1.0075x over previous
//
#include <hip/hip_runtime.h>

typedef _Float16 f16x8 __attribute__((ext_vector_type(8)));
typedef _Float16 f16x4 __attribute__((ext_vector_type(4)));
typedef _Float16 h2   __attribute__((ext_vector_type(2)));
typedef float f32x4 __attribute__((ext_vector_type(4)));

__device__ __forceinline__ void gload16(const void* g, void* l) {
  __builtin_amdgcn_global_load_lds(
      (__attribute__((address_space(1))) void*)g,
      (__attribute__((address_space(3))) void*)l, 16, 0, 0);
}

// W is scaled by 2^12 when cast to f16 (raw ~1e-5 values are f16-subnormal;
// denormal flush would delete the r@W term). Epilogue multiplies by 2^-12.
#define W_SCALE 4096.0f
#define W_UNSCALE (1.0f / 4096.0f)

// "Island" layout (LDS-fragment-exact), used for W_in (B operand):
// element (row,k) -> (row>>4)*50176 + (k>>5)*512 + ((k>>3)&3)*128 + (row&15)*8 + (k&7)
#define ISL(row, k) (((row) >> 4) * 50176 + ((k) >> 5) * 512 + \
                     ((((k) >> 3) & 3) << 7) + (((row) & 15) << 3) + ((k) & 7))

// ---------------- conv 3x3 (1->16) + bias + relu + maxpool2 -> conv_flat (plain) ----------
__global__ __launch_bounds__(256) void conv_pool_kernel(
    const float* __restrict__ x,      // [8192][28][28]
    const float* __restrict__ cw,     // [16][9]
    const float* __restrict__ cb,     // [16]
    _Float16* __restrict__ out) {     // [8192][3136] plain (c*196 + p)
  __shared__ float img[30 * 32];      // padded 30 rows x 32 cols (row/col +1 offset)
  __shared__ h2 wsm[144];
  __shared__ h2 bsm[16];
  int tid = threadIdx.x;
  for (int i = tid; i < 960; i += 256) img[i] = 0.f;
  if (tid < 144) { float w = cw[tid]; wsm[tid] = h2{(_Float16)w, (_Float16)w}; }
  if (tid < 16)  { float b = cb[tid]; bsm[tid] = h2{(_Float16)b, (_Float16)b}; }
  __syncthreads();
  if (tid < 196) {                    // 28 rows x 7 float4 per row
    float4 v = *(const float4*)(x + (size_t)blockIdx.x * 784 + tid * 4);
    int row = tid / 7, col4 = (tid - row * 7) * 4;
    float* dst = img + (row + 1) * 32 + col4 + 1;
    dst[0] = v.x; dst[1] = v.y; dst[2] = v.z; dst[3] = v.w;
  }
  __syncthreads();
  if (tid >= 196) return;
  int ph = tid / 14, pw = tid - ph * 14;
  const float* base = img + (2 * ph) * 32 + (2 * pw);
  h2 xp[4][3];
#pragma unroll
  for (int i = 0; i < 4; ++i) {
    float r0 = base[i * 32 + 0], r1 = base[i * 32 + 1];
    float r2 = base[i * 32 + 2], r3 = base[i * 32 + 3];
    xp[i][0] = h2{(_Float16)r0, (_Float16)r1};
    xp[i][1] = h2{(_Float16)r1, (_Float16)r2};
    xp[i][2] = h2{(_Float16)r2, (_Float16)r3};
  }
  _Float16* orow = out + (size_t)blockIdx.x * 3136 + tid;
#pragma unroll
  for (int ch = 0; ch < 16; ++ch) {
    h2 a01 = bsm[ch], a23 = bsm[ch];
#pragma unroll
    for (int i = 0; i < 3; ++i)
#pragma unroll
      for (int j = 0; j < 3; ++j) {
        h2 wv = wsm[ch * 9 + i * 3 + j];
        a01 = __builtin_elementwise_fma(wv, xp[i][j], a01);
        a23 = __builtin_elementwise_fma(wv, xp[i + 1][j], a23);
      }
    h2 m2 = __builtin_elementwise_max(a01, a23);
    _Float16 m = m2[0] > m2[1] ? m2[0] : m2[1];
    m = m > (_Float16)0.f ? m : (_Float16)0.f;
    orow[ch * 196] = m;
  }
}

// ---------------- prep: W_in -> island f16  |  W -> Wt f16 (n-major, *2^12) -------------
__global__ __launch_bounds__(256) void prep_kernel(
    const float* __restrict__ W_in, _Float16* __restrict__ W_in_h,
    const float* __restrict__ W, _Float16* __restrict__ Wt) {
  int b = blockIdx.x, tid = threadIdx.x;
  if (b < 256) {
    const float* src = W_in + (size_t)b * 3136;
#pragma unroll
    for (int it = 0; it < 4; ++it) {
      int idx = it * 256 + tid;          // float4 index, 784 per row
      if (idx < 784) {
        int k0 = idx * 4;
        float4 v = *(const float4*)(src + k0);
        f16x4 h = {(_Float16)v.x, (_Float16)v.y, (_Float16)v.z, (_Float16)v.w};
        *(f16x4*)(W_in_h + ISL(b, k0)) = h;
      }
    }
  } else {
    int i = (b - 256) * 256 + tid;       // 65536
    int k = i >> 8, n = i & 255;         // coalesced read of W row k
    Wt[n * 256 + k] = (_Float16)(W[k * 256 + n] * W_SCALE);
  }
}

// ---------------- GEMM1 split-K=2: Zz = A @ W_in^T, 64x64 dbuf, 4 blocks/CU -------------
// grid (128,4,2); BK=32, 49 steps; 4 waves x (32x32 = 2x2 frags).
// A: plain global -> island LDS via per-lane-address global_load_lds.
// B: island global -> linear global_load_lds. Stage t+1 issued before compute t.
__global__ __launch_bounds__(256) void gemm1_kernel(
    const _Float16* __restrict__ A,   // plain [8192][3136]
    const _Float16* __restrict__ Bw,  // island, logical [256][3136]
    float* __restrict__ Z) {          // [2][8192][256] partials
  __shared__ __align__(16) _Float16 As[2][2048];   // 4 chunks [kg][row][8] x dbuf
  __shared__ __align__(16) _Float16 Bs[2][2048];
  int tid = threadIdx.x, lane = tid & 63, wid = tid >> 6;
  int bm = blockIdx.x * 64, bn = blockIdx.y * 64;
  int k0 = blockIdx.z * 1568;
  f32x4 acc[2][2];
#pragma unroll
  for (int i = 0; i < 2; ++i)
#pragma unroll
    for (int j = 0; j < 2; ++j) acc[i][j] = (f32x4){0.f, 0.f, 0.f, 0.f};

  // wave w stages A-chunk w (rows w*16..+16) and B-chunk w (cols w*16..+16)
  const _Float16* Ag = A + (size_t)(bm + wid * 16 + (lane & 15)) * 3136
                         + k0 + ((lane >> 4) << 3);
  const _Float16* Bg = Bw + (size_t)((bn >> 4) + wid) * 50176
                         + ((k0 >> 5) << 9) + lane * 8;

  int rko = ((lane >> 4) << 7) + ((lane & 15) << 3);
  int ga = (wid & 1) * 2, gb = (wid >> 1) * 2;

  // prologue: stage t=0 into buf0
  gload16(Ag, &As[0][wid * 512]);
  gload16(Bg, &Bs[0][wid * 512]);
  __syncthreads();                     // buf0 ready

  int cur = 0;
  for (int t = 0; t < 49; ++t) {
    if (t < 48) {                      // stage t+1 into other buffer, issued EARLY
      gload16(Ag + (t + 1) * 32,           &As[cur ^ 1][wid * 512]);
      gload16(Bg + (size_t)(t + 1) * 512,  &Bs[cur ^ 1][wid * 512]);
    }
    f16x8 af0 = *(const f16x8*)(&As[cur][(ga + 0) * 512 + rko]);
    f16x8 af1 = *(const f16x8*)(&As[cur][(ga + 1) * 512 + rko]);
    f16x8 bf0 = *(const f16x8*)(&Bs[cur][(gb + 0) * 512 + rko]);
    f16x8 bf1 = *(const f16x8*)(&Bs[cur][(gb + 1) * 512 + rko]);
    acc[0][0] = __builtin_amdgcn_mfma_f32_16x16x32_f16(af0, bf0, acc[0][0], 0, 0, 0);
    acc[0][1] = __builtin_amdgcn_mfma_f32_16x16x32_f16(af0, bf1, acc[0][1], 0, 0, 0);
    acc[1][0] = __builtin_amdgcn_mfma_f32_16x16x32_f16(af1, bf0, acc[1][0], 0, 0, 0);
    acc[1][1] = __builtin_amdgcn_mfma_f32_16x16x32_f16(af1, bf1, acc[1][1], 0, 0, 0);
    __syncthreads();                   // drains stage(t+1), guards buf reuse; TLP covers
    cur ^= 1;
  }

  float* Zp = Z + (size_t)blockIdx.z * 8192 * 256;
  int wm = (wid & 1) * 32, wn = (wid >> 1) * 32;
  int rg = (lane >> 4) * 4, cl = lane & 15;
#pragma unroll
  for (int mi = 0; mi < 2; ++mi)
#pragma unroll
    for (int ni = 0; ni < 2; ++ni)
#pragma unroll
      for (int j = 0; j < 4; ++j) {
        int m = bm + wm + mi * 16 + rg + j;
        int n = bn + wn + ni * 16 + cl;
        Zp[(size_t)m * 256 + n] = acc[mi][ni][j];
      }
}

// ---------------- persistent RNN: r0=relu(Z0+Z1+b); 9x r=relu(r@W+b+r); out-proj -------
// Z read ONCE: f16 r0 staged to LDS, f32 residual extracted from LDS image.
__global__ __launch_bounds__(512, 2) void rnn_persist_kernel(
    const float*    __restrict__ Z0,   // [8192][256] k-half 0 partial
    const float*    __restrict__ Z1,   // [8192][256] k-half 1 partial
    const _Float16* __restrict__ Wt,   // [256][256] n-major, *2^12
    const float*    __restrict__ b_in, // [256]
    const float*    __restrict__ Wo,   // [10][256]
    const float*    __restrict__ bo,   // [10]
    float*          __restrict__ out)  // [8192][10]
{
  // element (row,k) stored at row*256 + (k ^ ((row&7)<<3))  [16B-granular]
  __shared__ __align__(16) _Float16 r_lds[32 * 256];
  int tid = threadIdx.x, lane = tid & 63, wid = tid >> 6;
  int wr = wid >> 2, wc = wid & 3;       // 2M x 4N wave grid; region 16r x 64c
  int bm = blockIdx.x * 32;

  // ---- W fragments -> registers (one-time) ----
  f16x8 wfr[8][4];
#pragma unroll
  for (int kk = 0; kk < 8; ++kk)
#pragma unroll
    for (int ni = 0; ni < 4; ++ni) {
      int n = wc * 64 + ni * 16 + (lane & 15);
      int kpos = kk * 32 + (lane >> 4) * 8;
      wfr[kk][ni] = *(const f16x8*)(Wt + n * 256 + kpos);
    }

  // ---- r0 = relu(Z0+Z1+b) f16 -> LDS (swizzled): single Z read ----
#pragma unroll
  for (int it = 0; it < 2; ++it) {
    int idx = it * 512 + tid;            // 0..1023
    int row = idx >> 5;                  // 0..31
    int kc = (idx & 31) * 8;             // 0..248
    size_t off = (size_t)(bm + row) * 256 + kc;
    f32x4 a0 = *(const f32x4*)(Z0 + off);
    f32x4 a1 = *(const f32x4*)(Z0 + off + 4);
    f32x4 b0 = *(const f32x4*)(Z1 + off);
    f32x4 b1 = *(const f32x4*)(Z1 + off + 4);
    f32x4 c0 = *(const f32x4*)(b_in + kc);
    f32x4 c1 = *(const f32x4*)(b_in + kc + 4);
    f16x8 h;
#pragma unroll
    for (int j = 0; j < 4; ++j) h[j] = (_Float16)fmaxf(a0[j] + b0[j] + c0[j], 0.f);
#pragma unroll
    for (int j = 0; j < 4; ++j) h[4 + j] = (_Float16)fmaxf(a1[j] + b1[j] + c1[j], 0.f);
    *(f16x8*)(r_lds + row * 256 + (kc ^ ((row & 7) << 3))) = h;
  }
  __syncthreads();                       // r0 image complete

  // ---- bias + f32 residual extracted from LDS (one f16 rounding on r0) ----
  float breg[4];
  float rres[4][4];
  int rrow = wr * 16 + (lane >> 4) * 4;
#pragma unroll
  for (int ni = 0; ni < 4; ++ni) {
    int col = wc * 64 + ni * 16 + (lane & 15);
    breg[ni] = b_in[col];
#pragma unroll
    for (int j = 0; j < 4; ++j) {
      int row = rrow + j;
      rres[ni][j] = (float)r_lds[row * 256 + (col ^ ((row & 7) << 3))];
    }
  }

  int arow = wr * 16 + (lane & 15);
  int aswz = (arow & 7) << 3;
  for (int s = 0; s < 9; ++s) {
    __syncthreads();                     // r_lds writes visible
    f32x4 acc[4];
#pragma unroll
    for (int ni = 0; ni < 4; ++ni) acc[ni] = (f32x4){0.f, 0.f, 0.f, 0.f};
#pragma unroll
    for (int kk = 0; kk < 8; ++kk) {
      int kpos = kk * 32 + (lane >> 4) * 8;
      f16x8 af = *(const f16x8*)(r_lds + arow * 256 + (kpos ^ aswz));
#pragma unroll
      for (int ni = 0; ni < 4; ++ni)
        acc[ni] = __builtin_amdgcn_mfma_f32_16x16x32_f16(af, wfr[kk][ni], acc[ni], 0, 0, 0);
    }
    __syncthreads();                     // all reads done before overwrite
#pragma unroll
    for (int ni = 0; ni < 4; ++ni) {
      int col = wc * 64 + ni * 16 + (lane & 15);
#pragma unroll
      for (int j = 0; j < 4; ++j) {
        float v = fmaxf(fmaf(acc[ni][j], W_UNSCALE, breg[ni] + rres[ni][j]), 0.f);
        rres[ni][j] = v;
        int row = rrow + j;
        r_lds[row * 256 + (col ^ ((row & 7) << 3))] = (_Float16)v;
      }
    }
  }
  __syncthreads();

  // ---- fused out-proj: out[32r][10] = r @ Wo^T + bo ----
  if (tid < 320) {
    int row = tid / 10, o = tid - row * 10;
    int rswz = (row & 7) << 3;
    float accd = 0.f;
    for (int kc = 0; kc < 256; kc += 8) {
      f16x8 rv = *(const f16x8*)(r_lds + row * 256 + (kc ^ rswz));
      const float* wp = Wo + o * 256 + kc;
#pragma unroll
      for (int j = 0; j < 8; ++j) accd = fmaf((float)rv[j], wp[j], accd);
    }
    out[(size_t)(bm + row) * 10 + o] = accd + bo[o];
  }
}

extern "C" void kernel_launch(void* const* d_in, const int* in_sizes, int n_in,
                              void* d_out, int out_size, void* d_ws, size_t ws_size,
                              hipStream_t stream) {
  const float* x      = (const float*)d_in[0];
  const float* conv_w = (const float*)d_in[1];
  const float* conv_b = (const float*)d_in[2];
  const float* W_in   = (const float*)d_in[3];
  const float* b_in   = (const float*)d_in[4];
  const float* W_out  = (const float*)d_in[5];
  const float* b_out  = (const float*)d_in[6];
  const float* W      = (const float*)d_in[7];
  float* out = (float*)d_out;

  char* ws = (char*)d_ws;
  size_t o = 0;
  _Float16* conv_flat = (_Float16*)(ws + o); o += (size_t)8192 * 3136 * 2;  // 51.4MB plain
  _Float16* W_in_h    = (_Float16*)(ws + o); o += (size_t)256 * 3136 * 2;   //  1.6MB island
  _Float16* Wt_h      = (_Float16*)(ws + o); o += (size_t)256 * 256 * 2;    //  0.13MB
  float*    Z01       = (float*)(ws + o);    o += (size_t)2 * 8192 * 256 * 4; // 16.8MB partials

  prep_kernel<<<512, 256, 0, stream>>>(W_in, W_in_h, W, Wt_h);
  conv_pool_kernel<<<8192, 256, 0, stream>>>(x, conv_w, conv_b, conv_flat);
  gemm1_kernel<<<dim3(128, 4, 2), 256, 0, stream>>>(conv_flat, W_in_h, Z01);
  rnn_persist_kernel<<<256, 512, 0, stream>>>(Z01, Z01 + (size_t)8192 * 256,
                                              Wt_h, b_in, W_out, b_out, out);
}